// Round 8
// baseline (483.992 us; speedup 1.0000x reference)
//
#include <hip/hip_runtime.h>
#include <hip/hip_bf16.h>

#define SQ 2048
#define HH 2048
#define NHEAD 16
#define HD 128
#define QKVW (NHEAD*3*HD)   // 6144

typedef __attribute__((ext_vector_type(8))) short bf16x8;
typedef __attribute__((ext_vector_type(4))) float f32x4;
typedef __attribute__((ext_vector_type(16))) float f32x16;

__device__ inline unsigned short f2bf(float f) {
    union { float f; unsigned u; } x; x.f = f;
    unsigned r = x.u + 0x7FFFu + ((x.u >> 16) & 1u);
    return (unsigned short)(r >> 16);
}

__device__ inline unsigned pack_bf2(float a, float b) {
    return (unsigned)f2bf(a) | ((unsigned)f2bf(b) << 16);
}

__device__ inline float gelu_f(float x) {
    float x3 = x * (1.f + 0.044715f * x * x);
    return 0.5f * x * (1.f + tanhf(0.79788456f * x3));
}

// async global->LDS, 16B per lane. lds must be wave-uniform; g is per-lane.
__device__ inline void gld16(void* lds, const void* g) {
    __builtin_amdgcn_global_load_lds(
        (__attribute__((address_space(1))) void*)(g),
        (__attribute__((address_space(3))) void*)(lds), 16, 0, 0);
}

// ---------------- LayerNorm: fp32 in -> bf16 out ----------------
__global__ __launch_bounds__(256) void ln_kernel(
    const float* __restrict__ in, const float* __restrict__ g,
    const float* __restrict__ b, unsigned short* __restrict__ out)
{
    int row = blockIdx.x;
    int t = threadIdx.x, lane = t & 63, wid = t >> 6;
    const float4* rp = (const float4*)(in + (size_t)row * HH);
    float4 v0 = rp[t], v1 = rp[t + 256];
    float s  = v0.x + v0.y + v0.z + v0.w + v1.x + v1.y + v1.z + v1.w;
    float ss = v0.x*v0.x + v0.y*v0.y + v0.z*v0.z + v0.w*v0.w
             + v1.x*v1.x + v1.y*v1.y + v1.z*v1.z + v1.w*v1.w;
    #pragma unroll
    for (int o = 32; o; o >>= 1) { s += __shfl_down(s, o); ss += __shfl_down(ss, o); }
    __shared__ float r0[4], r1[4];
    if (lane == 0) { r0[wid] = s; r1[wid] = ss; }
    __syncthreads();
    s  = r0[0] + r0[1] + r0[2] + r0[3];
    ss = r1[0] + r1[1] + r1[2] + r1[3];
    float mu = s * (1.f / HH);
    float var = ss * (1.f / HH) - mu * mu;
    float rs = rsqrtf(var + 1e-5f);
    float4 g0 = ((const float4*)g)[t], g1 = ((const float4*)g)[t + 256];
    float4 b0 = ((const float4*)b)[t], b1 = ((const float4*)b)[t + 256];
    ushort4 o0, o1;
    o0.x = f2bf((v0.x - mu) * rs * g0.x + b0.x);
    o0.y = f2bf((v0.y - mu) * rs * g0.y + b0.y);
    o0.z = f2bf((v0.z - mu) * rs * g0.z + b0.z);
    o0.w = f2bf((v0.w - mu) * rs * g0.w + b0.w);
    o1.x = f2bf((v1.x - mu) * rs * g1.x + b1.x);
    o1.y = f2bf((v1.y - mu) * rs * g1.y + b1.y);
    o1.z = f2bf((v1.z - mu) * rs * g1.z + b1.z);
    o1.w = f2bf((v1.w - mu) * rs * g1.w + b1.w);
    ushort4* op = (ushort4*)(out + (size_t)row * HH);
    op[t] = o0; op[t + 256] = o1;
}

// ---------------- reduce: out = sum(4 partials) + res + bias ----------------
__global__ __launch_bounds__(256) void reduce4_kernel(
    const float* __restrict__ p0, const float* __restrict__ p1,
    const float* __restrict__ p2, const float* __restrict__ p3,
    const float* __restrict__ res, const float* __restrict__ bias,
    float* __restrict__ out, int n4, int nc4m1)
{
    int i = blockIdx.x * blockDim.x + threadIdx.x;
    int st = gridDim.x * blockDim.x;
    for (; i < n4; i += st) {
        float4 a = ((const float4*)p0)[i];
        float4 b = ((const float4*)p1)[i];
        float4 c = ((const float4*)p2)[i];
        float4 d = ((const float4*)p3)[i];
        float4 r = ((const float4*)res)[i];
        float4 bv = ((const float4*)bias)[i & nc4m1];
        float4 o;
        o.x = a.x + b.x + c.x + d.x + r.x + bv.x;
        o.y = a.y + b.y + c.y + d.y + r.y + bv.y;
        o.z = a.z + b.z + c.z + d.z + r.z + bv.z;
        o.w = a.w + b.w + c.w + d.w + r.w + bv.w;
        ((float4*)out)[i] = o;
    }
}

// =============== 256x128 GEMM, BK=32, 2 blocks/CU, fp32-B folded ===============
// C[M,N] = A[M,K]bf16 @ B[N,K]fp32^T (converted in-kernel). 512 thr = 8 waves
// (2M x 4N); per-wave C 128x32 (8x2 16x16 frags, 64 acc VGPR).
// LDS: A[2][256][32] linear (gld16, chunk-XOR s(r)=(r&3)^((r>>2)&3) both sides),
//      B[2][128][40] padded (reg-staged fp32->bf16). 52 KiB -> 2 blocks/CU.
// Per K-tile: {issue B-fp32 loads + A gld16 for t+1} {frag ds_reads + 16 MFMA}
// {pack+ds_write B(t+1)} __syncthreads(). Loads issued at tile top drain at
// tile end; the co-resident independent block fills the stalls (m114 TLP).

// MODE: 0 = fp32 partial (no bias), 1 = bf16 + bias (+GELU), 2 = QKV splitV
template<int MODE, int GELU_ON>
__global__ __launch_bounds__(512, 4) void gemm256(
    const unsigned short* __restrict__ A, const float* __restrict__ B,
    const float* __restrict__ bias, void* __restrict__ outp,
    unsigned short* __restrict__ vtb, void* __restrict__ outp_hi,
    int N, int lda, int ldb, int kLen, int CH, int CW)
{
    __shared__ __align__(16) unsigned short Asm[2][256][32];   // 32 KiB
    __shared__ __align__(16) unsigned short Bsm[2][128][40];   // 20.5 KiB

    int t = threadIdx.x, lane = t & 63, wid = t >> 6;
    int lo = lane & 15, hi = lane >> 4;
    int wr = wid >> 2, wc = wid & 3;

    // 2D chunked XCD swizzle over (R = bz*gy+by, bx); CHxCW rectangle per XCD.
    int id = (blockIdx.z * gridDim.y + blockIdx.y) * gridDim.x + blockIdx.x;
    int xcd = id & 7, local = id >> 3;
    int cgx = gridDim.x / CW;
    int cr = xcd / cgx, cc = xcd - cr * cgx;
    int lr = local / CW, lc = local - lr * CW;
    int R  = cr * CH + lr;
    int bn = cc * CW + lc;
    int bm = R % gridDim.y;
    int bz = R / gridDim.y;
    int m0 = bm * 256, n0 = bn * 128;
    int kstart = bz * kLen;
    int nt = kLen >> 5;                     // BK = 32, always exact

    // staging maps
    int rA0 = wid * 16 + (lane >> 2);       // A rows (first gld16); +128 second
    int sAc = lane & 3;                     // A lds chunk (16B units)
    int rB = t >> 2, pB = t & 3;            // B row, 8-float part

    const unsigned short* Abase = A + (size_t)m0 * lda + kstart;
    int s0 = (rA0 & 3) ^ ((rA0 >> 2) & 3);  // == s(rA0+128)
    const unsigned short* Asrc0 = Abase + (size_t)rA0 * lda + ((sAc ^ s0) << 3);
    const unsigned short* Asrc1 = Abase + (size_t)(rA0 + 128) * lda + ((sAc ^ s0) << 3);
    const float* Bsrc = B + (size_t)(n0 + rB) * ldb + kstart + pB * 8;

    // ---- prologue: stage tile 0 into buf 0
    {
        float4 b0 = *(const float4*)(Bsrc);
        float4 b1 = *(const float4*)(Bsrc + 4);
        gld16(&Asm[0][wid * 16][0], Asrc0);
        gld16(&Asm[0][128 + wid * 16][0], Asrc1);
        int4 w;
        w.x = (int)pack_bf2(b0.x, b0.y); w.y = (int)pack_bf2(b0.z, b0.w);
        w.z = (int)pack_bf2(b1.x, b1.y); w.w = (int)pack_bf2(b1.z, b1.w);
        *(int4*)&Bsm[0][rB][pB * 8] = w;
        __syncthreads();
    }

    f32x4 acc[8][2] = {};
    for (int u = 0; u < nt; u++) {
        int buf = u & 1, nbuf = buf ^ 1;
        int t1 = (u + 1 < nt) ? u + 1 : u;  // clamp: last iter re-stages (dead)
        // issue next-tile staging
        float4 b0 = *(const float4*)(Bsrc + t1 * 32);
        float4 b1 = *(const float4*)(Bsrc + t1 * 32 + 4);
        gld16(&Asm[nbuf][wid * 16][0], Asrc0 + t1 * 32);
        gld16(&Asm[nbuf][128 + wid * 16][0], Asrc1 + t1 * 32);
        // compute current tile
        __builtin_amdgcn_s_setprio(1);
        const unsigned short (*LA)[32] = Asm[buf];
        const unsigned short (*LB)[40] = Bsm[buf];
        bf16x8 bfr0 = *(const bf16x8*)&LB[wc * 32 + lo][hi * 8];
        bf16x8 bfr1 = *(const bf16x8*)&LB[wc * 32 + 16 + lo][hi * 8];
        #pragma unroll
        for (int i = 0; i < 8; i++) {
            int rA = wr * 128 + i * 16 + lo;
            bf16x8 af = *(const bf16x8*)&LA[rA][(hi ^ ((rA & 3) ^ ((rA >> 2) & 3))) << 3];
            acc[i][0] = __builtin_amdgcn_mfma_f32_16x16x32_bf16(bfr0, af, acc[i][0], 0, 0, 0);
            acc[i][1] = __builtin_amdgcn_mfma_f32_16x16x32_bf16(bfr1, af, acc[i][1], 0, 0, 0);
        }
        __builtin_amdgcn_s_setprio(0);
        // write staged B (compiler waits the fp32 loads here)
        int4 w;
        w.x = (int)pack_bf2(b0.x, b0.y); w.y = (int)pack_bf2(b0.z, b0.w);
        w.z = (int)pack_bf2(b1.x, b1.y); w.w = (int)pack_bf2(b1.z, b1.w);
        *(int4*)&Bsm[nbuf][rB][pB * 8] = w;
        __syncthreads();                    // drains vm (gld16) + lgkm
    }

    // ---- epilogue ----  acc[i][c][j]: row M = m0+wr*128+i*16+lo,
    //                     col N = n0+wc*32+c*16+hi*4+j (j contiguous in N)
    if (MODE == 0) {
        float* po = ((bz < 2) ? (float*)outp : (float*)outp_hi)
                  + (size_t)(bz & 1) * SQ * (size_t)N;
        #pragma unroll
        for (int i = 0; i < 8; i++) {
            int gr = m0 + wr * 128 + i * 16 + lo;
            #pragma unroll
            for (int c = 0; c < 2; c++) {
                int gc = n0 + wc * 32 + c * 16 + hi * 4;
                *(f32x4*)&po[(size_t)gr * N + gc] = acc[i][c];
            }
        }
    } else if (MODE == 1) {
        unsigned short* op = (unsigned short*)outp;
        #pragma unroll
        for (int i = 0; i < 8; i++) {
            int gr = m0 + wr * 128 + i * 16 + lo;
            #pragma unroll
            for (int c = 0; c < 2; c++) {
                int gc = n0 + wc * 32 + c * 16 + hi * 4;
                float4 bi = *(const float4*)&bias[gc];
                float v0 = acc[i][c][0] + bi.x, v1 = acc[i][c][1] + bi.y;
                float v2 = acc[i][c][2] + bi.z, v3 = acc[i][c][3] + bi.w;
                if (GELU_ON) { v0 = gelu_f(v0); v1 = gelu_f(v1); v2 = gelu_f(v2); v3 = gelu_f(v3); }
                ushort4 o; o.x = f2bf(v0); o.y = f2bf(v1); o.z = f2bf(v2); o.w = f2bf(v3);
                *(ushort4*)&op[(size_t)gr * N + gc] = o;
            }
        }
    } else {
        // QKV: tile (128 cols) is entirely q, k, or v of head bn/3
        unsigned short* op = (unsigned short*)outp;
        int head = n0 / 384;
        int cat = (n0 >> 7) % 3;
        #pragma unroll
        for (int i = 0; i < 8; i++) {
            int gr = m0 + wr * 128 + i * 16 + lo;
            #pragma unroll
            for (int c = 0; c < 2; c++) {
                int gc = n0 + wc * 32 + c * 16 + hi * 4;
                float4 bi = *(const float4*)&bias[gc];
                float v0 = acc[i][c][0] + bi.x, v1 = acc[i][c][1] + bi.y;
                float v2 = acc[i][c][2] + bi.z, v3 = acc[i][c][3] + bi.w;
                if (cat == 2) {             // V columns -> transposed store
                    int d = wc * 32 + c * 16 + hi * 4;
                    unsigned short* vp = vtb + (size_t)(head * HD + d) * SQ + gr;
                    vp[0]      = f2bf(v0);
                    vp[SQ]     = f2bf(v1);
                    vp[2 * SQ] = f2bf(v2);
                    vp[3 * SQ] = f2bf(v3);
                } else {
                    ushort4 o; o.x = f2bf(v0); o.y = f2bf(v1); o.z = f2bf(v2); o.w = f2bf(v3);
                    *(ushort4*)&op[(size_t)gr * N + gc] = o;
                }
            }
        }
    }
}

// ---------------- Flash attention: 32x32 MFMA, causal + alibi ----------------
__global__ __launch_bounds__(128) void attn_kernel(
    const unsigned short* __restrict__ qkvB,  // [S][6144] bf16 (q,k valid)
    const unsigned short* __restrict__ vtb,   // [NH][HD][S] bf16
    unsigned short* __restrict__ ctx)         // [S][2048] bf16
{
    int w = blockIdx.x;
    int lid = (w & 7) * 64 + (w >> 3);
    int n = lid >> 5, qt = lid & 31;
    int t = threadIdx.x, lane = t & 63, wid = t >> 6;
    int l32 = lane & 31, h2 = lane >> 5;
    int q0 = qt * 64, qg = q0 + wid * 32 + l32;

    __shared__ __align__(16) unsigned short Ks[64][128];
    __shared__ __align__(16) unsigned short Vt[128][64];

    bf16x8 qf[8];
    const unsigned short* qp = qkvB + (size_t)qg * QKVW + n * 384 + h2 * 8;
    #pragma unroll
    for (int d8 = 0; d8 < 8; d8++)
        qf[d8] = *(const bf16x8*)(qp + d8 * 16);

    const float slope = exp2f(-0.5f * (float)(n + 1));
    const float inv = 0.08838834764831845f;   // 1/sqrt(128)
    float m = -INFINITY, lsum = 0.f;
    f32x16 ao[4] = {};

    int krow = lane >> 4, kch = lane & 15;
    int vrow = lane >> 3, vch = lane & 7;
    const unsigned short* kb_ = qkvB + n * 384 + 128;
    const unsigned short* vb_ = vtb + (size_t)n * HD * SQ;
    const char* ksb = (const char*)&Ks[0][0];
    const char* vsb = (const char*)&Vt[0][0];

    int nkb = qt + 1;
    for (int kb = 0; kb < nkb; kb++) {
        int k0 = kb * 64;
        __syncthreads();
        #pragma unroll
        for (int s = 0; s < 8; s++) {
            int r = wid * 32 + s * 4 + krow;
            gld16(&Ks[wid * 32 + s * 4][0],
                  kb_ + (size_t)(k0 + r) * QKVW + ((kch ^ (r & 7)) << 3));
            int dd = wid * 64 + s * 8 + vrow;
            gld16(&Vt[wid * 64 + s * 8][0],
                  vb_ + (size_t)dd * SQ + k0 + ((vch ^ (dd & 7)) << 3));
        }
        __syncthreads();

        f32x16 sc0 = {}, sc1 = {};
        #pragma unroll
        for (int d8 = 0; d8 < 8; d8++) {
            int ch = ((d8 * 2 + h2) ^ (l32 & 7)) << 4;
            bf16x8 kf0 = *(const bf16x8*)(ksb + l32 * 256 + ch);
            bf16x8 kf1 = *(const bf16x8*)(ksb + (32 + l32) * 256 + ch);
            sc0 = __builtin_amdgcn_mfma_f32_32x32x16_bf16(kf0, qf[d8], sc0, 0, 0, 0);
            sc1 = __builtin_amdgcn_mfma_f32_32x32x16_bf16(kf1, qf[d8], sc1, 0, 0, 0);
        }

        float tmax = -INFINITY;
        int last = (kb == nkb - 1);
        #pragma unroll
        for (int r = 0; r < 16; r++) {
            int kl = (r & 3) + 8 * (r >> 2) + 4 * h2;
            float s0 = sc0[r] * inv + slope * (float)(k0 + kl);
            float s1 = sc1[r] * inv + slope * (float)(k0 + 32 + kl);
            if (last) {
                if (k0 + kl > qg) s0 = -INFINITY;
                if (k0 + 32 + kl > qg) s1 = -INFINITY;
            }
            sc0[r] = s0; sc1[r] = s1;
            tmax = fmaxf(tmax, fmaxf(s0, s1));
        }
        tmax = fmaxf(tmax, __shfl_xor(tmax, 32));
        if (!__all(tmax <= m + 8.f)) {          // defer-max (T13)
            float mnew = fmaxf(m, tmax);
            float sca = __expf(m - mnew);
            m = mnew;
            lsum *= sca;
            #pragma unroll
            for (int db = 0; db < 4; db++)
                #pragma unroll
                for (int e = 0; e < 16; e++) ao[db][e] *= sca;
        }
        float psum = 0.f;
        #pragma unroll
        for (int r = 0; r < 16; r++) {
            sc0[r] = __expf(sc0[r] - m); psum += sc0[r];
            sc1[r] = __expf(sc1[r] - m); psum += sc1[r];
        }
        psum += __shfl_xor(psum, 32);
        lsum += psum;

        #pragma unroll
        for (int kstep = 0; kstep < 4; kstep++) {
            const int ks1 = kstep & 1;
            float a0, a1, a2, a3, b0, b1, b2, b3;
            if (kstep < 2) {
                a0 = sc0[8*ks1+0]; a1 = sc0[8*ks1+1]; a2 = sc0[8*ks1+2]; a3 = sc0[8*ks1+3];
                b0 = sc0[8*ks1+4]; b1 = sc0[8*ks1+5]; b2 = sc0[8*ks1+6]; b3 = sc0[8*ks1+7];
            } else {
                a0 = sc1[8*ks1+0]; a1 = sc1[8*ks1+1]; a2 = sc1[8*ks1+2]; a3 = sc1[8*ks1+3];
                b0 = sc1[8*ks1+4]; b1 = sc1[8*ks1+5]; b2 = sc1[8*ks1+6]; b3 = sc1[8*ks1+7];
            }
            unsigned ku0 = pack_bf2(h2 ? b0 : a0, h2 ? b1 : a1);
            unsigned ku1 = pack_bf2(h2 ? b2 : a2, h2 ? b3 : a3);
            unsigned su0 = pack_bf2(h2 ? a0 : b0, h2 ? a1 : b1);
            unsigned su1 = pack_bf2(h2 ? a2 : b2, h2 ? a3 : b3);
            unsigned r0 = (unsigned)__shfl_xor((int)su0, 32);
            unsigned r1 = (unsigned)__shfl_xor((int)su1, 32);
            union { int4 i; bf16x8 v; } u;
            u.i.x = h2 ? (int)r0  : (int)ku0;
            u.i.y = h2 ? (int)r1  : (int)ku1;
            u.i.z = h2 ? (int)ku0 : (int)r0;
            u.i.w = h2 ? (int)ku1 : (int)r1;
            bf16x8 pf = u.v;
            int ch = ((kstep * 2 + h2) ^ (l32 & 7)) << 4;
            #pragma unroll
            for (int db = 0; db < 4; db++) {
                bf16x8 vf = *(const bf16x8*)(vsb + (db * 32 + l32) * 128 + ch);
                ao[db] = __builtin_amdgcn_mfma_f32_32x32x16_bf16(vf, pf, ao[db], 0, 0, 0);
            }
        }
    }

    float rl = 1.f / lsum;
    #pragma unroll
    for (int db = 0; db < 4; db++)
        #pragma unroll
        for (int g = 0; g < 4; g++) {
            ushort4 o;
            o.x = f2bf(ao[db][g*4+0] * rl);
            o.y = f2bf(ao[db][g*4+1] * rl);
            o.z = f2bf(ao[db][g*4+2] * rl);
            o.w = f2bf(ao[db][g*4+3] * rl);
            *(ushort4*)(ctx + (size_t)qg * HH + n * HD + db * 32 + g * 8 + h2 * 4) = o;
        }
}

extern "C" void kernel_launch(void* const* d_in, const int* in_sizes, int n_in,
                              void* d_out, int out_size, void* d_ws, size_t ws_size,
                              hipStream_t stream) {
    const float* hs    = (const float*)d_in[0];
    const float* ln1g  = (const float*)d_in[4];
    const float* ln1b  = (const float*)d_in[5];
    const float* qkvw  = (const float*)d_in[6];
    const float* qkvb  = (const float*)d_in[7];
    const float* dw    = (const float*)d_in[8];
    const float* db    = (const float*)d_in[9];
    const float* ln2g  = (const float*)d_in[10];
    const float* ln2b  = (const float*)d_in[11];
    const float* f1w   = (const float*)d_in[12];
    const float* f1b   = (const float*)d_in[13];
    const float* f2w   = (const float*)d_in[14];
    const float* f2b   = (const float*)d_in[15];
    float* out = (float*)d_out;

    char* ws = (char*)d_ws;
    size_t off = 0;
    auto alloc = [&](size_t nbytes) {
        void* p = ws + off; off += (nbytes + 255) & ~(size_t)255; return p;
    };
    unsigned short* xbf  = (unsigned short*)alloc((size_t)SQ * HH * 2);        // [0, 8.4M)
    unsigned short* qkvB = (unsigned short*)alloc((size_t)SQ * QKVW * 2);      // [8.4M, 33.6M)
    unsigned short* vtB  = (unsigned short*)alloc((size_t)NHEAD * HD * SQ * 2);// [33.6M, 41.9M)
    unsigned short* ctx  = (unsigned short*)alloc((size_t)SQ * HH * 2);        // [41.9M, 50.3M)
    float*          attn = (float*)alloc((size_t)SQ * HH * 4);                 // [50.3M, 67.1M)
    unsigned short* y    = (unsigned short*)alloc((size_t)SQ * HH * 2);        // [67.1M, 75.5M)
    unsigned short* hdn  = (unsigned short*)alloc((size_t)SQ * 4 * HH * 2);    // [75.5M, 109.1M)
    float*          extra = (float*)alloc((size_t)2 * SQ * HH * 4);            // [109.1M, 142.6M)

    const size_t PQ = (size_t)SQ * HH;      // floats per partial (16.8 MB)
    float* part = (float*)ws;               // partials overlap dead early buffers

    ln_kernel<<<SQ, 256, 0, stream>>>(hs, ln1g, ln1b, xbf);

    // QKV: M=2048,N=6144,K=2048. grid 48x8 = 384 blocks; CH=4,CW=12.
    gemm256<2, 0><<<dim3(QKVW / 128, SQ / 256, 1), 512, 0, stream>>>(
        xbf, qkvw, qkvb, qkvB, vtB, nullptr, QKVW, HH, HH, HH, 4, 12);

    attn_kernel<<<512, 128, 0, stream>>>(qkvB, vtB, ctx);

    // dense: split-K x4 (512 blocks); partials p0,p1 at ws[0,33.6M), p2,p3 in dead hdn
    gemm256<0, 0><<<dim3(HH / 128, SQ / 256, 4), 512, 0, stream>>>(
        ctx, dw, nullptr, part, nullptr, hdn, HH, HH, HH, HH / 4, 8, 8);
    reduce4_kernel<<<2048, 256, 0, stream>>>(
        part, part + PQ, (float*)hdn, (float*)hdn + PQ, hs, db, attn, SQ * HH / 4, HH / 4 - 1);

    ln_kernel<<<SQ, 256, 0, stream>>>(attn, ln2g, ln2b, y);

    // FC1: M=2048,N=8192,K=2048. grid 64x8 = 512 blocks; CH=4,CW=16.
    gemm256<1, 1><<<dim3(4 * HH / 128, SQ / 256, 1), 512, 0, stream>>>(
        y, f1w, f1b, hdn, nullptr, nullptr, 4 * HH, HH, HH, HH, 4, 16);

    // FC2: split-K x4 (512 blocks, kLen=2048); p0,p1 at ws[0,33.6M), p2,p3 at extra
    gemm256<0, 0><<<dim3(HH / 128, SQ / 256, 4), 512, 0, stream>>>(
        hdn, f2w, nullptr, part, nullptr, extra, HH, 4 * HH, 4 * HH, HH, 8, 8);
    reduce4_kernel<<<2048, 256, 0, stream>>>(
        part, part + PQ, extra, extra + PQ, attn, f2b, out, SQ * HH / 4, HH / 4 - 1);
}

// Round 9
// 480.642 us; speedup vs baseline: 1.0070x; 1.0070x over previous
//
#include <hip/hip_runtime.h>
#include <hip/hip_bf16.h>

#define SQ 2048
#define HH 2048
#define NHEAD 16
#define HD 128
#define QKVW (NHEAD*3*HD)   // 6144

typedef __attribute__((ext_vector_type(8))) short bf16x8;
typedef __attribute__((ext_vector_type(4))) float f32x4;
typedef __attribute__((ext_vector_type(16))) float f32x16;

__device__ inline unsigned short f2bf(float f) {
    union { float f; unsigned u; } x; x.f = f;
    unsigned r = x.u + 0x7FFFu + ((x.u >> 16) & 1u);
    return (unsigned short)(r >> 16);
}

__device__ inline unsigned pack_bf2(float a, float b) {
    return (unsigned)f2bf(a) | ((unsigned)f2bf(b) << 16);
}

__device__ inline float gelu_f(float x) {
    float x3 = x * (1.f + 0.044715f * x * x);
    return 0.5f * x * (1.f + tanhf(0.79788456f * x3));
}

// async global->LDS, 16B per lane. lds must be wave-uniform; g is per-lane.
__device__ inline void gld16(void* lds, const void* g) {
    __builtin_amdgcn_global_load_lds(
        (__attribute__((address_space(1))) void*)(g),
        (__attribute__((address_space(3))) void*)(lds), 16, 0, 0);
}

// ---------------- LayerNorm: fp32 in -> bf16 out ----------------
__global__ __launch_bounds__(256) void ln_kernel(
    const float* __restrict__ in, const float* __restrict__ g,
    const float* __restrict__ b, unsigned short* __restrict__ out)
{
    int row = blockIdx.x;
    int t = threadIdx.x, lane = t & 63, wid = t >> 6;
    const float4* rp = (const float4*)(in + (size_t)row * HH);
    float4 v0 = rp[t], v1 = rp[t + 256];
    float s  = v0.x + v0.y + v0.z + v0.w + v1.x + v1.y + v1.z + v1.w;
    float ss = v0.x*v0.x + v0.y*v0.y + v0.z*v0.z + v0.w*v0.w
             + v1.x*v1.x + v1.y*v1.y + v1.z*v1.z + v1.w*v1.w;
    #pragma unroll
    for (int o = 32; o; o >>= 1) { s += __shfl_down(s, o); ss += __shfl_down(ss, o); }
    __shared__ float r0[4], r1[4];
    if (lane == 0) { r0[wid] = s; r1[wid] = ss; }
    __syncthreads();
    s  = r0[0] + r0[1] + r0[2] + r0[3];
    ss = r1[0] + r1[1] + r1[2] + r1[3];
    float mu = s * (1.f / HH);
    float var = ss * (1.f / HH) - mu * mu;
    float rs = rsqrtf(var + 1e-5f);
    float4 g0 = ((const float4*)g)[t], g1 = ((const float4*)g)[t + 256];
    float4 b0 = ((const float4*)b)[t], b1 = ((const float4*)b)[t + 256];
    ushort4 o0, o1;
    o0.x = f2bf((v0.x - mu) * rs * g0.x + b0.x);
    o0.y = f2bf((v0.y - mu) * rs * g0.y + b0.y);
    o0.z = f2bf((v0.z - mu) * rs * g0.z + b0.z);
    o0.w = f2bf((v0.w - mu) * rs * g0.w + b0.w);
    o1.x = f2bf((v1.x - mu) * rs * g1.x + b1.x);
    o1.y = f2bf((v1.y - mu) * rs * g1.y + b1.y);
    o1.z = f2bf((v1.z - mu) * rs * g1.z + b1.z);
    o1.w = f2bf((v1.w - mu) * rs * g1.w + b1.w);
    ushort4* op = (ushort4*)(out + (size_t)row * HH);
    op[t] = o0; op[t + 256] = o1;
}

// ---------------- reduce: out = sum(4 partials) + res + bias ----------------
__global__ __launch_bounds__(256) void reduce4_kernel(
    const float* __restrict__ p0, const float* __restrict__ p1,
    const float* __restrict__ p2, const float* __restrict__ p3,
    const float* __restrict__ res, const float* __restrict__ bias,
    float* __restrict__ out, int n4, int nc4m1)
{
    int i = blockIdx.x * blockDim.x + threadIdx.x;
    int st = gridDim.x * blockDim.x;
    for (; i < n4; i += st) {
        float4 a = ((const float4*)p0)[i];
        float4 b = ((const float4*)p1)[i];
        float4 c = ((const float4*)p2)[i];
        float4 d = ((const float4*)p3)[i];
        float4 r = ((const float4*)res)[i];
        float4 bv = ((const float4*)bias)[i & nc4m1];
        float4 o;
        o.x = a.x + b.x + c.x + d.x + r.x + bv.x;
        o.y = a.y + b.y + c.y + d.y + r.y + bv.y;
        o.z = a.z + b.z + c.z + d.z + r.z + bv.z;
        o.w = a.w + b.w + c.w + d.w + r.w + bv.w;
        ((float4*)out)[i] = o;
    }
}

// ========== 256x128 GEMM, BK=32, 3-buffer depth-2 pipeline, fp32-B folded =====
// C[M,N] = A[M,K]bf16 @ B[N,K]fp32^T (converted in-kernel). 512 thr = 8 waves
// (2M x 4N); per-wave C 128x32 (8x2 16x16 frags).
// LDS: Asm[3][256][32] (gld16, chunk-XOR sA(r)=(r&3)^((r>>2)&3)),
//      Bsm[3][128][32] (reg-staged fp32->bf16, chunk-XOR sB(r)=r&3). 72 KiB
//      -> 2 blocks/CU.
// Pipeline (iter u): stage A(u+2)->slot[u+2]; load B(u+2)->regs; ds_write aged
// B(u+1) (loads 1 iter old); compute tile u; lgkmcnt(0) publish; vmcnt(4)
// (A(u+2)+B(u+2) stay in flight); raw s_barrier. Depth-2 for A, ~1.5 for B.
// Ledger: A slot (u+2)%3 last read iter u-1 (1 bar ago) OK. B slot (u+1)%3
// last read iter u-2 (2 bars) OK. vmcnt(4) at bar drains A(u+1) (read next).

// MODE: 0 = fp32 partial (no bias), 1 = bf16 + bias (+GELU), 2 = QKV splitV
template<int MODE, int GELU_ON>
__global__ __launch_bounds__(512, 4) void gemm256(
    const unsigned short* __restrict__ A, const float* __restrict__ B,
    const float* __restrict__ bias, void* __restrict__ outp,
    unsigned short* __restrict__ vtb, void* __restrict__ outp_hi,
    int N, int lda, int ldb, int kLen, int CH, int CW)
{
    __shared__ __align__(16) unsigned short Asm[3][256][32];   // 48 KiB
    __shared__ __align__(16) unsigned short Bsm[3][128][32];   // 24 KiB

    int t = threadIdx.x, lane = t & 63, wid = t >> 6;
    int lo = lane & 15, hi = lane >> 4;
    int wr = wid >> 2, wc = wid & 3;

    // 2D chunked XCD swizzle over (R = bz*gy+by, bx); CHxCW rectangle per XCD.
    int id = (blockIdx.z * gridDim.y + blockIdx.y) * gridDim.x + blockIdx.x;
    int xcd = id & 7, local = id >> 3;
    int cgx = gridDim.x / CW;
    int cr = xcd / cgx, cc = xcd - cr * cgx;
    int lr = local / CW, lc = local - lr * CW;
    int R  = cr * CH + lr;
    int bn = cc * CW + lc;
    int bm = R % gridDim.y;
    int bz = R / gridDim.y;
    int m0 = bm * 256, n0 = bn * 128;
    int kstart = bz * kLen;
    int nt = kLen >> 5;                     // BK = 32

    // staging maps
    int rA0 = wid * 16 + (lane >> 2);       // A rows (first gld16); +128 second
    int sAc = lane & 3;                     // A lds chunk
    int rB = t >> 2, pB = t & 3;            // B row, 8-float part

    const unsigned short* Abase = A + (size_t)m0 * lda + kstart;
    int s0 = (rA0 & 3) ^ ((rA0 >> 2) & 3);  // == sA(rA0+128)
    const unsigned short* Asrc0 = Abase + (size_t)rA0 * lda + ((sAc ^ s0) << 3);
    const unsigned short* Asrc1 = Abase + (size_t)(rA0 + 128) * lda + ((sAc ^ s0) << 3);
    const float* Bsrc = B + (size_t)(n0 + rB) * ldb + kstart + pB * 8;
    int wBc = (pB ^ (rB & 3)) << 3;         // swizzled write chunk (elems)

    // ---- prologue: A(0),A(1) in flight; B(0),B(1) loaded; B(0),B(1) written
    gld16(&Asm[0][wid * 16][0], Asrc0);
    gld16(&Asm[0][128 + wid * 16][0], Asrc1);
    float4 c0 = *(const float4*)(Bsrc);
    float4 c1 = *(const float4*)(Bsrc + 4);
    int k1 = (nt > 1) ? 32 : 0;
    gld16(&Asm[1][wid * 16][0], Asrc0 + k1);
    gld16(&Asm[1][128 + wid * 16][0], Asrc1 + k1);
    float4 d0 = *(const float4*)(Bsrc + k1);
    float4 d1 = *(const float4*)(Bsrc + k1 + 4);
    {
        int4 w;
        w.x = (int)pack_bf2(c0.x, c0.y); w.y = (int)pack_bf2(c0.z, c0.w);
        w.z = (int)pack_bf2(c1.x, c1.y); w.w = (int)pack_bf2(c1.z, c1.w);
        *(int4*)&Bsm[0][rB][wBc] = w;
    }
    float4 bo0 = d0, bo1 = d1;              // aged B = tile 1
    asm volatile("s_waitcnt vmcnt(2) lgkmcnt(0)" ::: "memory"); // A(0) done; A(1) may fly
    __builtin_amdgcn_s_barrier();

    f32x4 acc[8][2] = {};
    int sl0 = 0, sl1 = 1, sl2 = 2;          // rotating slots: cur, next, stage
    for (int u = 0; u < nt; u++) {
        int t2 = (u + 2 < nt) ? u + 2 : nt - 1;
        // stage A(t2) into slot sl2
        gld16(&Asm[sl2][wid * 16][0], Asrc0 + t2 * 32);
        gld16(&Asm[sl2][128 + wid * 16][0], Asrc1 + t2 * 32);
        // load B(t2) fp32 -> regs
        float4 bn0 = *(const float4*)(Bsrc + t2 * 32);
        float4 bn1 = *(const float4*)(Bsrc + t2 * 32 + 4);
        // write aged B(u+1) -> slot sl1 (its loads are 1 iteration old)
        {
            int4 w;
            w.x = (int)pack_bf2(bo0.x, bo0.y); w.y = (int)pack_bf2(bo0.z, bo0.w);
            w.z = (int)pack_bf2(bo1.x, bo1.y); w.w = (int)pack_bf2(bo1.z, bo1.w);
            *(int4*)&Bsm[sl1][rB][wBc] = w;
        }
        // compute tile u from slot sl0
        __builtin_amdgcn_s_setprio(1);
        {
            const unsigned short (*LA)[32] = Asm[sl0];
            const unsigned short (*LB)[32] = Bsm[sl0];
            int rB0 = wc * 32 + lo, rB1 = wc * 32 + 16 + lo;
            bf16x8 bfr0 = *(const bf16x8*)&LB[rB0][(hi ^ (rB0 & 3)) << 3];
            bf16x8 bfr1 = *(const bf16x8*)&LB[rB1][(hi ^ (rB1 & 3)) << 3];
            #pragma unroll
            for (int i = 0; i < 8; i++) {
                int rA = wr * 128 + i * 16 + lo;
                bf16x8 af = *(const bf16x8*)&LA[rA][(hi ^ ((rA & 3) ^ ((rA >> 2) & 3))) << 3];
                acc[i][0] = __builtin_amdgcn_mfma_f32_16x16x32_bf16(bfr0, af, acc[i][0], 0, 0, 0);
                acc[i][1] = __builtin_amdgcn_mfma_f32_16x16x32_bf16(bfr1, af, acc[i][1], 0, 0, 0);
            }
        }
        __builtin_amdgcn_s_setprio(0);
        bo0 = bn0; bo1 = bn1;
        // publish ds_write; keep A(t2)+B(t2) (4 loads) in flight
        asm volatile("s_waitcnt vmcnt(4) lgkmcnt(0)" ::: "memory");
        __builtin_amdgcn_s_barrier();
        int tmp = sl0; sl0 = sl1; sl1 = sl2; sl2 = tmp;
    }

    // ---- epilogue ----  acc[i][c][j]: row M = m0+wr*128+i*16+lo,
    //                     col N = n0+wc*32+c*16+hi*4+j (j contiguous in N)
    if (MODE == 0) {
        float* po = ((bz < 2) ? (float*)outp : (float*)outp_hi)
                  + (size_t)(bz & 1) * SQ * (size_t)N;
        #pragma unroll
        for (int i = 0; i < 8; i++) {
            int gr = m0 + wr * 128 + i * 16 + lo;
            #pragma unroll
            for (int c = 0; c < 2; c++) {
                int gc = n0 + wc * 32 + c * 16 + hi * 4;
                *(f32x4*)&po[(size_t)gr * N + gc] = acc[i][c];
            }
        }
    } else if (MODE == 1) {
        unsigned short* op = (unsigned short*)outp;
        #pragma unroll
        for (int i = 0; i < 8; i++) {
            int gr = m0 + wr * 128 + i * 16 + lo;
            #pragma unroll
            for (int c = 0; c < 2; c++) {
                int gc = n0 + wc * 32 + c * 16 + hi * 4;
                float4 bi = *(const float4*)&bias[gc];
                float v0 = acc[i][c][0] + bi.x, v1 = acc[i][c][1] + bi.y;
                float v2 = acc[i][c][2] + bi.z, v3 = acc[i][c][3] + bi.w;
                if (GELU_ON) { v0 = gelu_f(v0); v1 = gelu_f(v1); v2 = gelu_f(v2); v3 = gelu_f(v3); }
                ushort4 o; o.x = f2bf(v0); o.y = f2bf(v1); o.z = f2bf(v2); o.w = f2bf(v3);
                *(ushort4*)&op[(size_t)gr * N + gc] = o;
            }
        }
    } else {
        // QKV: tile (128 cols) is entirely q, k, or v of head bn/3
        unsigned short* op = (unsigned short*)outp;
        int head = n0 / 384;
        int cat = (n0 >> 7) % 3;
        #pragma unroll
        for (int i = 0; i < 8; i++) {
            int gr = m0 + wr * 128 + i * 16 + lo;
            #pragma unroll
            for (int c = 0; c < 2; c++) {
                int gc = n0 + wc * 32 + c * 16 + hi * 4;
                float4 bi = *(const float4*)&bias[gc];
                float v0 = acc[i][c][0] + bi.x, v1 = acc[i][c][1] + bi.y;
                float v2 = acc[i][c][2] + bi.z, v3 = acc[i][c][3] + bi.w;
                if (cat == 2) {             // V columns -> transposed store
                    int d = wc * 32 + c * 16 + hi * 4;
                    unsigned short* vp = vtb + (size_t)(head * HD + d) * SQ + gr;
                    vp[0]      = f2bf(v0);
                    vp[SQ]     = f2bf(v1);
                    vp[2 * SQ] = f2bf(v2);
                    vp[3 * SQ] = f2bf(v3);
                } else {
                    ushort4 o; o.x = f2bf(v0); o.y = f2bf(v1); o.z = f2bf(v2); o.w = f2bf(v3);
                    *(ushort4*)&op[(size_t)gr * N + gc] = o;
                }
            }
        }
    }
}

// ---------------- Flash attention: 32x32 MFMA, causal + alibi ----------------
__global__ __launch_bounds__(128) void attn_kernel(
    const unsigned short* __restrict__ qkvB,  // [S][6144] bf16 (q,k valid)
    const unsigned short* __restrict__ vtb,   // [NH][HD][S] bf16
    unsigned short* __restrict__ ctx)         // [S][2048] bf16
{
    int w = blockIdx.x;
    int lid = (w & 7) * 64 + (w >> 3);
    int n = lid >> 5, qt = lid & 31;
    int t = threadIdx.x, lane = t & 63, wid = t >> 6;
    int l32 = lane & 31, h2 = lane >> 5;
    int q0 = qt * 64, qg = q0 + wid * 32 + l32;

    __shared__ __align__(16) unsigned short Ks[64][128];
    __shared__ __align__(16) unsigned short Vt[128][64];

    bf16x8 qf[8];
    const unsigned short* qp = qkvB + (size_t)qg * QKVW + n * 384 + h2 * 8;
    #pragma unroll
    for (int d8 = 0; d8 < 8; d8++)
        qf[d8] = *(const bf16x8*)(qp + d8 * 16);

    const float slope = exp2f(-0.5f * (float)(n + 1));
    const float inv = 0.08838834764831845f;   // 1/sqrt(128)
    float m = -INFINITY, lsum = 0.f;
    f32x16 ao[4] = {};

    int krow = lane >> 4, kch = lane & 15;
    int vrow = lane >> 3, vch = lane & 7;
    const unsigned short* kb_ = qkvB + n * 384 + 128;
    const unsigned short* vb_ = vtb + (size_t)n * HD * SQ;
    const char* ksb = (const char*)&Ks[0][0];
    const char* vsb = (const char*)&Vt[0][0];

    int nkb = qt + 1;
    for (int kb = 0; kb < nkb; kb++) {
        int k0 = kb * 64;
        __syncthreads();
        #pragma unroll
        for (int s = 0; s < 8; s++) {
            int r = wid * 32 + s * 4 + krow;
            gld16(&Ks[wid * 32 + s * 4][0],
                  kb_ + (size_t)(k0 + r) * QKVW + ((kch ^ (r & 7)) << 3));
            int dd = wid * 64 + s * 8 + vrow;
            gld16(&Vt[wid * 64 + s * 8][0],
                  vb_ + (size_t)dd * SQ + k0 + ((vch ^ (dd & 7)) << 3));
        }
        __syncthreads();

        f32x16 sc0 = {}, sc1 = {};
        #pragma unroll
        for (int d8 = 0; d8 < 8; d8++) {
            int ch = ((d8 * 2 + h2) ^ (l32 & 7)) << 4;
            bf16x8 kf0 = *(const bf16x8*)(ksb + l32 * 256 + ch);
            bf16x8 kf1 = *(const bf16x8*)(ksb + (32 + l32) * 256 + ch);
            sc0 = __builtin_amdgcn_mfma_f32_32x32x16_bf16(kf0, qf[d8], sc0, 0, 0, 0);
            sc1 = __builtin_amdgcn_mfma_f32_32x32x16_bf16(kf1, qf[d8], sc1, 0, 0, 0);
        }

        float tmax = -INFINITY;
        int last = (kb == nkb - 1);
        #pragma unroll
        for (int r = 0; r < 16; r++) {
            int kl = (r & 3) + 8 * (r >> 2) + 4 * h2;
            float s0 = sc0[r] * inv + slope * (float)(k0 + kl);
            float s1 = sc1[r] * inv + slope * (float)(k0 + 32 + kl);
            if (last) {
                if (k0 + kl > qg) s0 = -INFINITY;
                if (k0 + 32 + kl > qg) s1 = -INFINITY;
            }
            sc0[r] = s0; sc1[r] = s1;
            tmax = fmaxf(tmax, fmaxf(s0, s1));
        }
        tmax = fmaxf(tmax, __shfl_xor(tmax, 32));
        if (!__all(tmax <= m + 8.f)) {          // defer-max (T13)
            float mnew = fmaxf(m, tmax);
            float sca = __expf(m - mnew);
            m = mnew;
            lsum *= sca;
            #pragma unroll
            for (int db = 0; db < 4; db++)
                #pragma unroll
                for (int e = 0; e < 16; e++) ao[db][e] *= sca;
        }
        float psum = 0.f;
        #pragma unroll
        for (int r = 0; r < 16; r++) {
            sc0[r] = __expf(sc0[r] - m); psum += sc0[r];
            sc1[r] = __expf(sc1[r] - m); psum += sc1[r];
        }
        psum += __shfl_xor(psum, 32);
        lsum += psum;

        #pragma unroll
        for (int kstep = 0; kstep < 4; kstep++) {
            const int ks1 = kstep & 1;
            float a0, a1, a2, a3, b0, b1, b2, b3;
            if (kstep < 2) {
                a0 = sc0[8*ks1+0]; a1 = sc0[8*ks1+1]; a2 = sc0[8*ks1+2]; a3 = sc0[8*ks1+3];
                b0 = sc0[8*ks1+4]; b1 = sc0[8*ks1+5]; b2 = sc0[8*ks1+6]; b3 = sc0[8*ks1+7];
            } else {
                a0 = sc1[8*ks1+0]; a1 = sc1[8*ks1+1]; a2 = sc1[8*ks1+2]; a3 = sc1[8*ks1+3];
                b0 = sc1[8*ks1+4]; b1 = sc1[8*ks1+5]; b2 = sc1[8*ks1+6]; b3 = sc1[8*ks1+7];
            }
            unsigned ku0 = pack_bf2(h2 ? b0 : a0, h2 ? b1 : a1);
            unsigned ku1 = pack_bf2(h2 ? b2 : a2, h2 ? b3 : a3);
            unsigned su0 = pack_bf2(h2 ? a0 : b0, h2 ? a1 : b1);
            unsigned su1 = pack_bf2(h2 ? a2 : b2, h2 ? a3 : b3);
            unsigned r0 = (unsigned)__shfl_xor((int)su0, 32);
            unsigned r1 = (unsigned)__shfl_xor((int)su1, 32);
            union { int4 i; bf16x8 v; } u;
            u.i.x = h2 ? (int)r0  : (int)ku0;
            u.i.y = h2 ? (int)r1  : (int)ku1;
            u.i.z = h2 ? (int)ku0 : (int)r0;
            u.i.w = h2 ? (int)ku1 : (int)r1;
            bf16x8 pf = u.v;
            int ch = ((kstep * 2 + h2) ^ (l32 & 7)) << 4;
            #pragma unroll
            for (int db = 0; db < 4; db++) {
                bf16x8 vf = *(const bf16x8*)(vsb + (db * 32 + l32) * 128 + ch);
                ao[db] = __builtin_amdgcn_mfma_f32_32x32x16_bf16(vf, pf, ao[db], 0, 0, 0);
            }
        }
    }

    float rl = 1.f / lsum;
    #pragma unroll
    for (int db = 0; db < 4; db++)
        #pragma unroll
        for (int g = 0; g < 4; g++) {
            ushort4 o;
            o.x = f2bf(ao[db][g*4+0] * rl);
            o.y = f2bf(ao[db][g*4+1] * rl);
            o.z = f2bf(ao[db][g*4+2] * rl);
            o.w = f2bf(ao[db][g*4+3] * rl);
            *(ushort4*)(ctx + (size_t)qg * HH + n * HD + db * 32 + g * 8 + h2 * 4) = o;
        }
}

extern "C" void kernel_launch(void* const* d_in, const int* in_sizes, int n_in,
                              void* d_out, int out_size, void* d_ws, size_t ws_size,
                              hipStream_t stream) {
    const float* hs    = (const float*)d_in[0];
    const float* ln1g  = (const float*)d_in[4];
    const float* ln1b  = (const float*)d_in[5];
    const float* qkvw  = (const float*)d_in[6];
    const float* qkvb  = (const float*)d_in[7];
    const float* dw    = (const float*)d_in[8];
    const float* db    = (const float*)d_in[9];
    const float* ln2g  = (const float*)d_in[10];
    const float* ln2b  = (const float*)d_in[11];
    const float* f1w   = (const float*)d_in[12];
    const float* f1b   = (const float*)d_in[13];
    const float* f2w   = (const float*)d_in[14];
    const float* f2b   = (const float*)d_in[15];
    float* out = (float*)d_out;

    char* ws = (char*)d_ws;
    size_t off = 0;
    auto alloc = [&](size_t nbytes) {
        void* p = ws + off; off += (nbytes + 255) & ~(size_t)255; return p;
    };
    unsigned short* xbf  = (unsigned short*)alloc((size_t)SQ * HH * 2);        // [0, 8.4M)
    unsigned short* qkvB = (unsigned short*)alloc((size_t)SQ * QKVW * 2);      // [8.4M, 33.6M)
    unsigned short* vtB  = (unsigned short*)alloc((size_t)NHEAD * HD * SQ * 2);// [33.6M, 41.9M)
    unsigned short* ctx  = (unsigned short*)alloc((size_t)SQ * HH * 2);        // [41.9M, 50.3M)
    float*          attn = (float*)alloc((size_t)SQ * HH * 4);                 // [50.3M, 67.1M)
    unsigned short* y    = (unsigned short*)alloc((size_t)SQ * HH * 2);        // [67.1M, 75.5M)
    unsigned short* hdn  = (unsigned short*)alloc((size_t)SQ * 4 * HH * 2);    // [75.5M, 109.1M)
    float*          extra = (float*)alloc((size_t)2 * SQ * HH * 4);            // [109.1M, 142.6M)

    const size_t PQ = (size_t)SQ * HH;      // floats per partial (16.8 MB)
    float* part = (float*)ws;               // partials overlap dead early buffers

    ln_kernel<<<SQ, 256, 0, stream>>>(hs, ln1g, ln1b, xbf);

    // QKV: M=2048,N=6144,K=2048. grid 48x8 = 384 blocks; CH=4,CW=12.
    gemm256<2, 0><<<dim3(QKVW / 128, SQ / 256, 1), 512, 0, stream>>>(
        xbf, qkvw, qkvb, qkvB, vtB, nullptr, QKVW, HH, HH, HH, 4, 12);

    attn_kernel<<<512, 128, 0, stream>>>(qkvB, vtB, ctx);

    // dense: split-K x4 (512 blocks); p0,p1 at ws[0,33.6M), p2,p3 in dead hdn
    gemm256<0, 0><<<dim3(HH / 128, SQ / 256, 4), 512, 0, stream>>>(
        ctx, dw, nullptr, part, nullptr, hdn, HH, HH, HH, HH / 4, 8, 8);
    reduce4_kernel<<<2048, 256, 0, stream>>>(
        part, part + PQ, (float*)hdn, (float*)hdn + PQ, hs, db, attn, SQ * HH / 4, HH / 4 - 1);

    ln_kernel<<<SQ, 256, 0, stream>>>(attn, ln2g, ln2b, y);

    // FC1: M=2048,N=8192,K=2048. grid 64x8 = 512 blocks; CH=4,CW=16.
    gemm256<1, 1><<<dim3(4 * HH / 128, SQ / 256, 1), 512, 0, stream>>>(
        y, f1w, f1b, hdn, nullptr, nullptr, 4 * HH, HH, HH, HH, 4, 16);

    // FC2: split-K x4 (512 blocks, kLen=2048); p0,p1 at ws[0,33.6M), p2,p3 at extra
    gemm256<0, 0><<<dim3(HH / 128, SQ / 256, 4), 512, 0, stream>>>(
        hdn, f2w, nullptr, part, nullptr, extra, HH, 4 * HH, 4 * HH, HH, 8, 8);
    reduce4_kernel<<<2048, 256, 0, stream>>>(
        part, part + PQ, extra, extra + PQ, attn, f2b, out, SQ * HH / 4, HH / 4 - 1);
}